// Round 11
// baseline (441.308 us; speedup 1.0000x reference)
//
#include <hip/hip_runtime.h>
#include <hip/hip_bf16.h>

// Problem constants (fixed by setup_inputs)
#define B_  2
#define C_  256
#define H_  64
#define W_  128
#define N_  (H_ * W_)   // 8192
#define K_  32          // top-k
#define Q_  24          // per-lane register queue depth
#define CK2 48          // candidates per row handed to stage 2 (bf16-sorted)
#define TN  32          // n-rows per block (2 strips x 16)
#define TM  32          // m-rows per half-tile
#define NHT 128         // tiles per m-half (4096/32)
#define MGP 193         // padded per-row stride (u32) in merge scratch

typedef short  short8  __attribute__((ext_vector_type(8)));
typedef short  short4v __attribute__((ext_vector_type(4)));
typedef float  floatx4 __attribute__((ext_vector_type(4)));

__device__ __forceinline__ unsigned umin_(unsigned a, unsigned b) { return a < b ? a : b; }
__device__ __forceinline__ unsigned umax_(unsigned a, unsigned b) { return a > b ? a : b; }
__device__ __forceinline__ ushort f2bf(float v) {
    __hip_bfloat16 h = __float2bfloat16(v);   // RNE
    ushort u; __builtin_memcpy(&u, &h, 2); return u;
}
// hardware median-of-3 (valid as shift-insert because q[i] <= q[i-1])
__device__ __forceinline__ unsigned med3u(unsigned a, unsigned b, unsigned c) {
    unsigned d;
    asm("v_med3_u32 %0, %1, %2, %3" : "=v"(d) : "v"(a), "v"(b), "v"(c));
    return d;
}

// key: top-19 bits of fp32 (clamped >=0, monotone) | 13-bit m index
__device__ __forceinline__ unsigned packkey(float v, int m) {
    const float vc = v > 0.0f ? v : 0.0f;
    unsigned b; __builtin_memcpy(&b, &vc, 4);
    return (b & 0xFFFFE000u) | (unsigned)m;
}

// descending-sorted register queue insert via v_med3_u32
__device__ __forceinline__ void qinsert(unsigned (&q)[Q_], unsigned k) {
#pragma unroll
    for (int i = Q_ - 1; i > 0; --i)
        q[i] = med3u(q[i - 1], k, q[i]);
    q[0] = umax_(q[0], k);
}

#define CSWAP(a, b) { const unsigned _mx = umax_(a, b); \
                      const unsigned _mn = umin_(a, b); (a) = _mx; (b) = _mn; }

// ---------------------------------------------------------------------------
// Kernel 1: prep (vectorized). fp32 [B][C][N] -> f1Tf fp32 [B][N][C],
//           f2Tf fp32 [B][N][C], f2T bf16 [B][N][C]
// ---------------------------------------------------------------------------
__global__ void raft_prep_kernel(const float* __restrict__ f1,
                                 const float* __restrict__ f2,
                                 float* __restrict__ f1Tf,
                                 ushort* __restrict__ f2T,
                                 float* __restrict__ f2Tf) {
    __shared__ float tile[32][33];
    const int nt = blockIdx.x;
    const int ct = blockIdx.y;
    const int z  = blockIdx.z;          // b*2 + which
    const int b  = z >> 1;
    const float* __restrict__ src = (z & 1) ? f2 : f1;
    const int tid = threadIdx.x;

    {
        const int cl = tid >> 3;        // 0..31
        const int nx = tid & 7;         // 0..7 (x4 n)
        const float4 v = *(const float4*)(
            src + ((size_t)b * C_ + (ct * 32 + cl)) * N_ + (nt * 32 + nx * 4));
        tile[cl][nx * 4 + 0] = v.x;
        tile[cl][nx * 4 + 1] = v.y;
        tile[cl][nx * 4 + 2] = v.z;
        tile[cl][nx * 4 + 3] = v.w;
    }
    __syncthreads();
    {
        const int nl = tid >> 3;        // 0..31
        const int c4 = (tid & 7) * 4;   // 0,4,..28
        float4 v;
        v.x = tile[c4 + 0][nl];
        v.y = tile[c4 + 1][nl];
        v.z = tile[c4 + 2][nl];
        v.w = tile[c4 + 3][nl];
        const size_t o = ((size_t)b * N_ + (nt * 32 + nl)) * C_ + (ct * 32 + c4);
        if (z & 1) {
            *(float4*)(f2Tf + o) = v;
            short4v h;
            h[0] = (short)f2bf(v.x); h[1] = (short)f2bf(v.y);
            h[2] = (short)f2bf(v.z); h[3] = (short)f2bf(v.w);
            *(short4v*)(f2T + o) = h;
        } else {
            *(float4*)(f1Tf + o) = v;
        }
    }
}

// ---------------------------------------------------------------------------
// Kernel 2: stage-1 — S^T MFMA + med3 register top-24 (m-split), 32 KB LDS
// (TM=32 half-tiles) for 4 blocks/CU. Tail: 8-way register-head merge per row
// -> bf16-sorted top-48 (membership identical to two-stage merge; keys unique).
// grid: 512 blocks, 256 threads = 4 waves (2 n-strips x 2 m-halves).
// ---------------------------------------------------------------------------
__launch_bounds__(256, 4)
__global__ void raft_stage1_kernel(const float* __restrict__ f1Tf,
                                   const ushort* __restrict__ f2T,
                                   ushort* __restrict__ cand) {
    __shared__ ushort Bt[2][TM * 256];   // 32,768 B: [half][32x256]

    const int bid  = blockIdx.x;
    const int b    = bid >> 8;                   // grid 512
    const int nt0  = (bid & 255) * TN;
    const int tid  = threadIdx.x;
    const int w    = tid >> 6;                   // 0..3
    const int s    = w >> 1;                     // n-strip 0..1
    const int h    = w & 1;                      // m-half 0..1
    const int lane = tid & 63;
    const int p    = lane & 15;
    const int q4   = lane >> 4;
    const int nrow = nt0 + s * 16 + p;
    const int mbase = h * (N_ / 2);
    const int lt   = s * 64 + lane;              // 0..127 within half-group

    // ---- f1 fragments (B-operand): fp32 -> bf16 RNE, 8 x short8 ----
    short8 af[8];
    {
        const float* __restrict__ arow = f1Tf + ((size_t)b * N_ + nrow) * C_;
        #pragma unroll
        for (int ks = 0; ks < 8; ++ks) {
            const float4 x = *(const float4*)(arow + ks * 32 + q4 * 8);
            const float4 y = *(const float4*)(arow + ks * 32 + q4 * 8 + 4);
            short8 t;
            t[0] = (short)f2bf(x.x); t[1] = (short)f2bf(x.y);
            t[2] = (short)f2bf(x.z); t[3] = (short)f2bf(x.w);
            t[4] = (short)f2bf(y.x); t[5] = (short)f2bf(y.y);
            t[6] = (short)f2bf(y.z); t[7] = (short)f2bf(y.w);
            af[ks] = t;
        }
    }

    unsigned q[Q_];
    #pragma unroll
    for (int i = 0; i < Q_; ++i) q[i] = 0u;

    const ushort* __restrict__ Bb = f2T + (size_t)b * N_ * C_ + (size_t)mbase * C_;

    // ---- preload tile 0 of this half (contiguous: elem offset = 8*idx) ----
    short8 stg[8];
    #pragma unroll
    for (int i = 0; i < 8; ++i)
        stg[i] = *(const short8*)(Bb + (size_t)8 * (lt + 128 * i));

    for (int mt = 0; mt < NHT; ++mt) {
        // ---- commit staged tile to LDS (swizzled) ----
        {
            ushort* __restrict__ dst = Bt[h];
            #pragma unroll
            for (int i = 0; i < 8; ++i) {
                const int idx = lt + 128 * i;    // 0..1023
                const int r   = idx >> 5;
                const int c8  = idx & 31;
                *(short8*)(&dst[(r * 32 + (c8 ^ (r & 7))) * 8]) = stg[i];
            }
        }
        __syncthreads();

        // ---- issue next-tile global loads (fly across MFMA + filter) ----
        if (mt < NHT - 1) {
            const ushort* __restrict__ src = Bb + (size_t)(mt + 1) * TM * C_;
            #pragma unroll
            for (int i = 0; i < 8; ++i)
                stg[i] = *(const short8*)(src + (size_t)8 * (lt + 128 * i));
        }

        // ---- MFMA: acc[f][r] = S^T[m = m0 + f*16 + q4*4 + r][n = nrow] ----
        const ushort* __restrict__ cur = Bt[h];
        floatx4 acc[2];
        #pragma unroll
        for (int f = 0; f < 2; ++f) acc[f] = (floatx4){0.f, 0.f, 0.f, 0.f};
        #pragma unroll
        for (int ks = 0; ks < 8; ++ks) {
            #pragma unroll
            for (int f = 0; f < 2; ++f) {
                const short8 bm = *(const short8*)(
                    &cur[((f * 16 + p) * 32 + ((ks * 4 + q4) ^ (p & 7))) * 8]);
                acc[f] = __builtin_amdgcn_mfma_f32_16x16x32_bf16(bm, af[ks], acc[f], 0, 0, 0);
            }
        }

        // ---- in-register filter ----
        const int m0 = mbase + mt * TM;
        #pragma unroll
        for (int f = 0; f < 2; ++f) {
            const int mb = m0 + f * 16 + q4 * 4;
            unsigned k0 = packkey(acc[f][0], mb + 0);
            unsigned k1 = packkey(acc[f][1], mb + 1);
            unsigned k2 = packkey(acc[f][2], mb + 2);
            unsigned k3 = packkey(acc[f][3], mb + 3);
            CSWAP(k0, k1); CSWAP(k2, k3); CSWAP(k0, k2); CSWAP(k1, k3); CSWAP(k1, k2);
            qinsert(q, k0);
            if (__any(k1 > q[Q_ - 1])) {
                qinsert(q, k1);
                if (__any(k2 > q[Q_ - 1])) {
                    qinsert(q, k2);
                    if (__any(k3 > q[Q_ - 1])) qinsert(q, k3);
                }
            }
        }
        __syncthreads();   // all reads done before next commit
    }

    // ---- tail: 8 sorted-24 lists per row -> top-48 via 8-way merge ----
    // mg[row][stream 0..7][24], row stride MGP=193 u32 (bank-spread), 24.7 KB
    unsigned* __restrict__ mg = (unsigned*)&Bt[0][0];
    const int rowl = s * 16 + p;
    const int st   = q4 * 2 + h;
    #pragma unroll
    for (int t = 0; t < Q_; ++t)
        mg[rowl * MGP + st * Q_ + t] = q[t];
    __syncthreads();

    if (tid < 32) {
        const unsigned* __restrict__ L = &mg[tid * MGP];
        unsigned head[8]; int nxt[8];
        #pragma unroll
        for (int k = 0; k < 8; ++k) { head[k] = L[k * Q_]; nxt[k] = 1; }
        ushort* __restrict__ myc = cand + ((size_t)(b * N_ + nt0 + tid)) * CK2;
        for (int t = 0; t < 48; ++t) {
            unsigned mx = head[0];
            #pragma unroll
            for (int k = 1; k < 8; ++k) mx = umax_(mx, head[k]);
            myc[t] = (ushort)(mx & 0x1FFFu);
            #pragma unroll
            for (int k = 0; k < 8; ++k) {
                const bool take = (head[k] == mx);
                const int  ix   = nxt[k] < Q_ ? nxt[k] : Q_ - 1;
                const unsigned nv = (nxt[k] < Q_) ? L[k * Q_ + ix] : 0u;
                head[k] = take ? nv : head[k];
                nxt[k] += take;
            }
        }
    }
}

// ---------------------------------------------------------------------------
// Kernel 3: stage-2 — fp32 sequential-FMA re-rank of 48 candidates + epilogue
// 8-deep float4 pipeline for MLP; FMA order (c ascending, single acc) exact.
// grid: B_*N_ = 16384 blocks, 64 threads
// ---------------------------------------------------------------------------
__launch_bounds__(64)
__global__ void raft_rerank_kernel(const float* __restrict__ f1Tf,  // [B][N][C]
                                   const float* __restrict__ f2Tf,  // [B][N][C]
                                   const ushort* __restrict__ cand, // [B*N][CK2]
                                   float* __restrict__ out) {
    __shared__ float  aS[C_];
    __shared__ float  cs[CK2];
    __shared__ ushort cmS[CK2];
    const int row = blockIdx.x;
    const int b   = row >> 13;
    const int n   = row & (N_ - 1);
    const int tid = threadIdx.x;       // 0..63

    if (tid < CK2) cmS[tid] = cand[(size_t)row * CK2 + tid];
    *(float4*)(&aS[tid * 4]) = *(const float4*)(f1Tf + ((size_t)b * N_ + n) * C_ + tid * 4);
    __syncthreads();

    if (tid < CK2) {
        const int m = cmS[tid];
        const float4* __restrict__ bRow4 =
            (const float4*)(f2Tf + ((size_t)b * N_ + m) * C_);
        float4 buf[8];
        #pragma unroll
        for (int j = 0; j < 8; ++j) buf[j] = bRow4[j];
        float acc = 0.0f;
        #pragma unroll
        for (int blk = 0; blk < 8; ++blk) {
            float4 nb[8];
            #pragma unroll
            for (int j = 0; j < 8; ++j)
                nb[j] = (blk < 7) ? bRow4[(blk + 1) * 8 + j] : buf[j];
            #pragma unroll
            for (int j = 0; j < 8; ++j) {
                const int c = blk * 32 + j * 4;
                acc = fmaf(aS[c + 0], buf[j].x, acc);
                acc = fmaf(aS[c + 1], buf[j].y, acc);
                acc = fmaf(aS[c + 2], buf[j].z, acc);
                acc = fmaf(aS[c + 3], buf[j].w, acc);
            }
            #pragma unroll
            for (int j = 0; j < 8; ++j) buf[j] = nb[j];
        }
        cs[tid] = acc;
    }
    __syncthreads();

    const int y0 = n >> 7, x0 = n & 127;
    if (tid < CK2) {
        const float v = cs[tid];
        const int m = cmS[tid];
        int rank = 0;
        for (int j = 0; j < CK2; ++j) {
            const float vj = cs[j];
            rank += (vj > v) || ((vj == v) && (cmS[j] < m));
        }
        if (rank < K_) {
            const size_t posn = (size_t)rank * N_ + n;
            out[(size_t)b * (K_ * N_) + posn] = v * 0.0625f;   // /sqrt(256), exact
            const size_t c1b = (size_t)1572864 + (size_t)b * 2 * K_ * N_;
            out[c1b + posn]                     = (float)((m >> 7) - y0);
            out[c1b + (size_t)(K_ * N_) + posn] = (float)((m & 127) - x0);
        }
    }
    if (tid < K_) {
        const size_t posn = (size_t)tid * N_ + n;
        const size_t c0b = (size_t)524288 + (size_t)b * 2 * K_ * N_;
        out[c0b + posn]                     = (float)y0;
        out[c0b + (size_t)(K_ * N_) + posn] = (float)x0;
        out[(size_t)2621440 + (size_t)b * (K_ * N_) + posn] = (float)b;
    }
}

// ---------------------------------------------------------------------------
extern "C" void kernel_launch(void* const* d_in, const int* in_sizes, int n_in,
                              void* d_out, int out_size, void* d_ws, size_t ws_size,
                              hipStream_t stream) {
    const float* f1 = (const float*)d_in[0];   // [B][C][N] fp32
    const float* f2 = (const float*)d_in[1];

    float*  f1Tf = (float*)d_ws;                             // 16,777,216 B
    float*  f2Tf = f1Tf + (size_t)B_ * N_ * C_;              // 16,777,216 B
    ushort* f2T  = (ushort*)(f2Tf + (size_t)B_ * N_ * C_);   //  8,388,608 B
    ushort* cand = f2T + (size_t)B_ * N_ * C_;               //  1,572,864 B

    raft_prep_kernel<<<dim3(N_ / 32, C_ / 32, B_ * 2), dim3(256), 0, stream>>>(
        f1, f2, f1Tf, f2T, f2Tf);

    raft_stage1_kernel<<<dim3(B_ * (N_ / TN)), dim3(256), 0, stream>>>(f1Tf, f2T, cand);

    raft_rerank_kernel<<<dim3(B_ * N_), dim3(64), 0, stream>>>(f1Tf, f2Tf, cand,
                                                               (float*)d_out);
}